// Round 3
// baseline (110.550 us; speedup 1.0000x reference)
//
#include <hip/hip_runtime.h>

#define N 8192
#define D 512
#define NFULL 1024                  // full 128x256 bricks: sum(2*bj2+1) = 32^2
#define NQ 64                       // 64 diagonal quarter-bricks (128x64)
#define NBRICKS (NFULL + NQ)
#define MARGIN 0.3f

typedef __attribute__((ext_vector_type(4))) int int4v;
typedef __attribute__((ext_vector_type(8))) int int8v;      // 32 fp8 = 8 VGPRs
typedef __attribute__((ext_vector_type(4))) float f32x4;    // MFMA accumulator

// async global->LDS, 16B per lane; LDS dest = wave-uniform base + lane*16.
__device__ __forceinline__ void gload_lds16(const void* g, void* l) {
    __builtin_amdgcn_global_load_lds(
        (const __attribute__((address_space(1))) void*)g,
        (__attribute__((address_space(3))) void*)l,
        16, 0, 0);
}

// Load one 16x16x128 f8f6f4 operand fragment (32 fp8 = 32 B) for (row, quad)
// from a 128 B/row LDS tile with 16B-chunk XOR swizzle (phys = logi ^ (row&7)).
__device__ __forceinline__ int8v load_frag8(const unsigned char* base, int row, int q) {
    const int v = (2 * q) ^ (row & 7);
    int4v lo = *(const int4v*)(base + row * 128 + v * 16);
    int4v hi = *(const int4v*)(base + row * 128 + (v ^ 1) * 16);
    return __builtin_shufflevector(lo, hi, 0, 1, 2, 3, 4, 5, 6, 7);
}

// Stage one BK=128 K-tile (A 128x128, B NCx128) with XOR source-swizzle.
// 512 threads: A = 2 gload_lds/wave, B = TNW gload_lds/wave -> (2+TNW)/wave/tile.
template <int TNW>
__device__ __forceinline__ void stage_tiles(const unsigned char* Ag, const unsigned char* Bg,
                                            unsigned char* Asm, unsigned char* Bsm,
                                            int tid, int k0) {
    #pragma unroll
    for (int s = 0; s < 2; s++) {                           // A: 1024 16B chunks
        int p = s * 512 + tid;
        int r = p >> 3, kc = (p & 7) ^ (r & 7);
        gload_lds16(Ag + (size_t)r * D + k0 + kc * 16, Asm + p * 16);
    }
    #pragma unroll
    for (int s = 0; s < TNW; s++) {                         // B: NC*8 chunks
        int p = s * 512 + tid;
        int r = p >> 3, kc = (p & 7) ^ (r & 7);
        gload_lds16(Bg + (size_t)r * D + k0 + kc * 16, Bsm + p * 16);
    }
}

// Kernel 1: per-row fp32 sum-of-squares (exact) + fp8(e4m3) cast + init.
__global__ void prep_kernel(const float* __restrict__ x,
                            unsigned char* __restrict__ x8,
                            float* __restrict__ sq,
                            unsigned int* __restrict__ apU,
                            unsigned int* __restrict__ anU,
                            int* __restrict__ cnt) {
    if (blockIdx.x == 0 && threadIdx.x == 0) cnt[0] = 0;
    int w = threadIdx.x >> 6, lane = threadIdx.x & 63;
    int row = blockIdx.x * 4 + w;
    const float4* p = (const float4*)(x + (size_t)row * D) + lane * 2;
    float4 v0 = p[0], v1 = p[1];
    float s = v0.x * v0.x + v0.y * v0.y + v0.z * v0.z + v0.w * v0.w
            + v1.x * v1.x + v1.y * v1.y + v1.z * v1.z + v1.w * v1.w;
    int w0 = __builtin_amdgcn_cvt_pk_fp8_f32(v0.x, v0.y, 0, false);
    w0     = __builtin_amdgcn_cvt_pk_fp8_f32(v0.z, v0.w, w0, true);
    int w1 = __builtin_amdgcn_cvt_pk_fp8_f32(v1.x, v1.y, 0, false);
    w1     = __builtin_amdgcn_cvt_pk_fp8_f32(v1.z, v1.w, w1, true);
    ((int2*)(x8 + (size_t)row * D))[lane] = make_int2(w0, w1);
    #pragma unroll
    for (int o = 32; o > 0; o >>= 1) s += __shfl_xor(s, o);
    if (lane == 0) {
        sq[row] = s;
        apU[row] = 0u;                 // max-d^2 accumulator (d^2 clamped >= 0)
        anU[row] = 0x7f800000u;        // min-d^2 accumulator (+inf)
    }
}

// Brick body, MX-fp8 (K=128) MFMA, 8 waves (2 row-halves x 4 col-quarters).
// TNW=4 -> 128x256 full brick; TNW=1 -> 128x64 diagonal quarter.
//
// T3+T4 K-loop: double-buffered LDS tiles, raw s_barrier, COUNTED vmcnt --
// never vmcnt(0) in steady state. Per-wave FIFO argument: tile t's (2+TNW)
// gload_lds are issued >= 2 tiles before they're consumed, so waiting to
// <= (2+TNW) outstanding guarantees tile t landed (anything newer is tile
// t+1's). barrier2 (lgkmcnt(0)+s_barrier) frees the buffer for tile t+2's
// stage. T5 setprio wraps the MFMA cluster (phases now exist).
// Gram-matrix property: A and B fragments use the SAME loader, so any
// consistent K-permutation cancels.
template <int TNW>
__device__ __forceinline__ void brick_body(
    int rowBase, int colBase,
    const unsigned char* __restrict__ xb, const float* __restrict__ sq,
    const int* __restrict__ tgt,
    unsigned int* __restrict__ apU, unsigned int* __restrict__ anU,
    char* smem_raw, float* sqI, float* sqJ, int* tI, int* tJ) {
    constexpr int NC = 64 * TNW;                            // brick cols
    constexpr int S = 16384 + NC * 128;                     // bytes per buffer
    unsigned char* A0 = (unsigned char*)smem_raw;
    unsigned char* B0 = A0 + 16384;
    unsigned char* A1 = A0 + S;
    unsigned char* B1 = A1 + 16384;
    float* redAp = (float*)smem_raw;                        // [128][66] (post-loop)
    float* redAn = redAp + 128 * 66;
    float* colAp = (float*)smem_raw;                        // [NC][10] (phase 2)
    float* colAn = colAp + NC * 10;

    const int tid = threadIdx.x;
    const int w = tid >> 6, lane = tid & 63, q = lane >> 4, c = lane & 15;
    const int wm = w & 1, wn = w >> 1;                      // 64-row x (TNW*16)-col/wave

    if (tid < 128) { sqI[tid] = sq[rowBase + tid]; tI[tid] = tgt[rowBase + tid]; }
    if (tid < NC)  { sqJ[tid] = sq[colBase + tid]; tJ[tid] = tgt[colBase + tid]; }

    const unsigned char* Ag = xb + (size_t)rowBase * D;
    const unsigned char* Bg = xb + (size_t)colBase * D;

    f32x4 acc[4][TNW] = {};

    stage_tiles<TNW>(Ag, Bg, A0, B0, tid, 0);               // tile 0
    stage_tiles<TNW>(Ag, Bg, A1, B1, tid, 128);             // tile 1

    #pragma unroll
    for (int kk = 0; kk < 4; kk++) {                        // 4 K-iterations
        unsigned char* Asm = (kk & 1) ? A1 : A0;
        unsigned char* Bsm = (kk & 1) ? B1 : B0;
        // barrier1: this wave's tile-kk chunks landed; then all waves'.
        if (kk < 3) {
            if constexpr (TNW == 4) asm volatile("s_waitcnt vmcnt(6)" ::: "memory");
            else                    asm volatile("s_waitcnt vmcnt(3)" ::: "memory");
        } else {
            asm volatile("s_waitcnt vmcnt(0)" ::: "memory");
        }
        __builtin_amdgcn_s_barrier();
        __builtin_amdgcn_sched_barrier(0);                  // nothing crosses

        int8v af[4];
        #pragma unroll
        for (int t = 0; t < 4; t++)
            af[t] = load_frag8(Asm, wm * 64 + t * 16 + c, q);
        int8v bf[TNW];
        #pragma unroll
        for (int t = 0; t < TNW; t++)
            bf[t] = load_frag8(Bsm, wn * (TNW * 16) + t * 16 + c, q);

        // barrier2: all waves' tile reads complete -> buffer free.
        asm volatile("s_waitcnt lgkmcnt(0)" ::: "memory");
        __builtin_amdgcn_s_barrier();
        __builtin_amdgcn_sched_barrier(0);

        if (kk < 2)                                         // tile kk+2 into freed buf
            stage_tiles<TNW>(Ag, Bg, Asm, Bsm, tid, (kk + 2) * 128);

        __builtin_amdgcn_s_setprio(1);
        #pragma unroll
        for (int tm = 0; tm < 4; tm++)
            #pragma unroll
            for (int t = 0; t < TNW; t++)
                acc[tm][t] = __builtin_amdgcn_mfma_scale_f32_16x16x128_f8f6f4(
                    af[tm], bf[t], acc[tm][t],
                    0, 0,                                    // FMT A,B = fp8 e4m3
                    0, 0x7F7F7F7Fu, 0, 0x7F7F7F7Fu);         // scales = 1.0
        __builtin_amdgcn_s_setprio(0);
    }

    // Epilogue. C/D layout is shape-determined: col=lane&15, row=q*4+reg.
    // Tiles are dead (all reads drained before iter-3 barrier2); scratch
    // aliases them. d^2-space selection keys.
    float sjc[TNW]; int tjx[TNW];
    #pragma unroll
    for (int tn = 0; tn < TNW; tn++) {
        int col_l = wn * (TNW * 16) + tn * 16 + c;
        sjc[tn] = sqJ[col_l]; tjx[tn] = tJ[col_l];
    }
    float apc[TNW], anc[TNW];
    #pragma unroll
    for (int tn = 0; tn < TNW; tn++) { apc[tn] = -1e30f; anc[tn] = 1e30f; }
    #pragma unroll
    for (int tm = 0; tm < 4; tm++) {
        #pragma unroll
        for (int r = 0; r < 4; r++) {
            int row_l = wm * 64 + tm * 16 + q * 4 + r;
            float si = sqI[row_l]; int ti = tI[row_l];
            float rp = -1e30f, rn = 1e30f;
            #pragma unroll
            for (int tn = 0; tn < TNW; tn++) {
                float p = acc[tm][tn][r];
                bool same = (ti == tjx[tn]);
                float rk = fmaf(-2.0f, p, sjc[tn]);         // row-side key
                float ck = fmaf(-2.0f, p, si);              // col-side key
                rp = fmaxf(rp, same ? rk : -1e30f);
                rn = fminf(rn, same ? 1e30f : rk);
                apc[tn] = fmaxf(apc[tn], same ? ck : -1e30f);
                anc[tn] = fminf(anc[tn], same ? 1e30f : ck);
            }
            redAp[row_l * 66 + wn * 16 + c] = rp;
            redAn[row_l * 66 + wn * 16 + c] = rn;
        }
    }
    __syncthreads();
    if (tid < 128) {                                        // row finalize
        float ap = -1e30f, an = 1e30f;
        #pragma unroll 8
        for (int u = 0; u < 64; u++) {
            ap = fmaxf(ap, redAp[tid * 66 + u]);
            an = fminf(an, redAn[tid * 66 + u]);
        }
        // restore true d^2, clamp >=0 so uint-bit compare == float compare
        float apd = fmaxf(sqI[tid] + ap, 0.0f);
        float and_ = fmaxf(sqI[tid] + an, 0.0f);
        atomicMax(&apU[rowBase + tid], __float_as_uint(apd));
        atomicMin(&anU[rowBase + tid], __float_as_uint(and_));
    }
    __syncthreads();                                        // row phase done
    #pragma unroll
    for (int tn = 0; tn < TNW; tn++) {
        int col_l = wn * (TNW * 16) + tn * 16 + c;
        colAp[col_l * 10 + wm * 4 + q] = apc[tn];
        colAn[col_l * 10 + wm * 4 + q] = anc[tn];
    }
    __syncthreads();
    if (tid < NC) {
        float ap = -1e30f, an = 1e30f;
        #pragma unroll
        for (int u = 0; u < 8; u++) {
            ap = fmaxf(ap, colAp[tid * 10 + u]);
            an = fminf(an, colAn[tid * 10 + u]);
        }
        float apd = fmaxf(sqJ[tid] + ap, 0.0f);
        float and_ = fmaxf(sqJ[tid] + an, 0.0f);
        atomicMax(&apU[colBase + tid], __float_as_uint(apd));  // fire-and-forget
        atomicMin(&anU[colBase + tid], __float_as_uint(and_));
    }
}

// Kernel 2: blocks 0..1023 = full bricks (bj2 = isqrt(id), bi = id - bj2^2);
// blocks 1024..1087 = diagonal quarter-bricks (128x64), dispatched LAST.
// 512 threads, 96 KB static LDS tile dbuf (+3 KB key arrays) -> 1 block/CU,
// 2 waves/SIMD (register-capped anyway; acc=64 AGPR/lane at TNW=4).
__global__ __launch_bounds__(512, 2)
void gemm_kernel(const unsigned char* __restrict__ xb,
                 const float* __restrict__ sq,
                 const int* __restrict__ tgt,
                 unsigned int* __restrict__ apU,
                 unsigned int* __restrict__ anU) {
    __shared__ __align__(16) char smem_raw[98304];          // 2 x (A 16K + B 32K)
    __shared__ float sqI[128], sqJ[256];
    __shared__ int tI[128], tJ[256];

    const int id = blockIdx.x;
    if (id < NFULL) {
        int bj2 = (int)sqrtf((float)id + 0.5f);
        while (bj2 * bj2 > id) bj2--;
        while ((bj2 + 1) * (bj2 + 1) <= id) bj2++;
        const int bi = id - bj2 * bj2;                      // 0..2*bj2
        brick_body<4>(bi * 128, bj2 * 256, xb, sq, tgt, apU, anU,
                      smem_raw, sqI, sqJ, tI, tJ);
    } else {
        const int h = id - NFULL;                           // 0..63
        const int j = h >> 1, side = h & 1;
        brick_body<1>((2 * j + 1) * 128, j * 256 + 128 + side * 64,
                      xb, sq, tgt, apU, anU, smem_raw, sqI, sqJ, tI, tJ);
    }
}

// Kernel 3: per-row ap/an final in apU/anU -> sqrt + relu + mean; last block
// (atomic counter) folds the 32 block sums into out[0].
__global__ void reduce_kernel(const unsigned int* __restrict__ apU,
                              const unsigned int* __restrict__ anU,
                              float* __restrict__ bsum, int* __restrict__ cnt,
                              float* __restrict__ out) {
    int tid = threadIdx.x;
    int row = blockIdx.x * 256 + tid;
    float ap = __uint_as_float(apU[row]);
    float an = __uint_as_float(anU[row]);
    float dap = sqrtf(fmaxf(ap, 1e-12f));
    float dan = sqrtf(fmaxf(an, 1e-12f));
    float v = fmaxf(dap - dan + MARGIN, 0.0f);
    #pragma unroll
    for (int o = 32; o > 0; o >>= 1) v += __shfl_xor(v, o);
    __shared__ float ss[4];
    __shared__ int amLast;
    if ((tid & 63) == 0) ss[tid >> 6] = v;
    __syncthreads();
    if (tid == 0) {
        bsum[blockIdx.x] = ss[0] + ss[1] + ss[2] + ss[3];
        __threadfence();
        amLast = (atomicAdd(cnt, 1) == N / 256 - 1);
    }
    __syncthreads();
    if (amLast && tid < 64) {
        __threadfence();
        float t = (tid < N / 256) ? bsum[tid] : 0.0f;
        #pragma unroll
        for (int o = 32; o > 0; o >>= 1) t += __shfl_xor(t, o);
        if (tid == 0) out[0] = t * (1.0f / (float)N);
    }
}

extern "C" void kernel_launch(void* const* d_in, const int* in_sizes, int n_in,
                              void* d_out, int out_size, void* d_ws, size_t ws_size,
                              hipStream_t stream) {
    const float* x  = (const float*)d_in[0];
    const int* tgt  = (const int*)d_in[1];
    float* out      = (float*)d_out;

    char* ws = (char*)d_ws;
    unsigned char* x8 = (unsigned char*)ws;                         // 4 MB fp8 X
    float* sq   = (float*)(ws + (size_t)N * D);                     // 32 KB
    unsigned int* apU = (unsigned int*)(sq + N);                    // 32 KB
    unsigned int* anU = apU + N;                                    // 32 KB
    float* bsum = (float*)(anU + N);                                // 128 B
    int* cnt = (int*)(bsum + 32);

    prep_kernel<<<N / 4, 256, 0, stream>>>(x, x8, sq, apU, anU, cnt);
    gemm_kernel<<<NBRICKS, 512, 0, stream>>>(x8, sq, tgt, apU, anU);
    reduce_kernel<<<N / 256, 256, 0, stream>>>(apU, anU, bsum, cnt, out);
}

// Round 4
// 105.572 us; speedup vs baseline: 1.0472x; 1.0472x over previous
//
#include <hip/hip_runtime.h>

#define N 8192
#define D 512
#define NFULLP 2016                 // off-diagonal 128x128 bricks: 64*63/2
#define NDIAG 64                    // diagonal 128x128 bricks
#define NBRICKS (NFULLP + NDIAG)
#define MARGIN 0.3f

typedef __attribute__((ext_vector_type(4))) int int4v;
typedef __attribute__((ext_vector_type(8))) int int8v;      // 32 fp8 = 8 VGPRs
typedef __attribute__((ext_vector_type(4))) float f32x4;    // MFMA accumulator

// async global->LDS, 16B per lane; LDS dest = wave-uniform base + lane*16.
__device__ __forceinline__ void gload_lds16(const void* g, void* l) {
    __builtin_amdgcn_global_load_lds(
        (const __attribute__((address_space(1))) void*)g,
        (__attribute__((address_space(3))) void*)l,
        16, 0, 0);
}

// Load one 16x16x128 f8f6f4 operand fragment (32 fp8 = 32 B) for (row, quad)
// from a 128 B/row LDS tile with 16B-chunk XOR swizzle (phys = logi ^ (row&7)).
__device__ __forceinline__ int8v load_frag8(const unsigned char* base, int row, int q) {
    const int v = (2 * q) ^ (row & 7);
    int4v lo = *(const int4v*)(base + row * 128 + v * 16);
    int4v hi = *(const int4v*)(base + row * 128 + (v ^ 1) * 16);
    return __builtin_shufflevector(lo, hi, 0, 1, 2, 3, 4, 5, 6, 7);
}

// Stage one BK=128 K-tile (A 128x128 + B 128x128 fp8) with XOR source-swizzle.
// 256 threads -> 8 gload_lds per thread per tile (4 A + 4 B).
__device__ __forceinline__ void stage_tile(const unsigned char* Ag, unsigned char* Asm,
                                           const unsigned char* Bg, unsigned char* Bsm,
                                           int tid, int k0) {
    #pragma unroll
    for (int s = 0; s < 4; s++) {                           // A: 1024 16B chunks
        int p = s * 256 + tid;
        int r = p >> 3, kc = (p & 7) ^ (r & 7);
        gload_lds16(Ag + (size_t)r * D + k0 + kc * 16, Asm + p * 16);
    }
    #pragma unroll
    for (int s = 0; s < 4; s++) {                           // B: 1024 16B chunks
        int p = s * 256 + tid;
        int r = p >> 3, kc = (p & 7) ^ (r & 7);
        gload_lds16(Bg + (size_t)r * D + k0 + kc * 16, Bsm + p * 16);
    }
}

// Kernel 1: per-row fp32 sum-of-squares (exact) + fp8(e4m3) cast + init.
__global__ void prep_kernel(const float* __restrict__ x,
                            unsigned char* __restrict__ x8,
                            float* __restrict__ sq,
                            unsigned int* __restrict__ apU,
                            unsigned int* __restrict__ anU,
                            int* __restrict__ cnt) {
    if (blockIdx.x == 0 && threadIdx.x == 0) cnt[0] = 0;
    int w = threadIdx.x >> 6, lane = threadIdx.x & 63;
    int row = blockIdx.x * 4 + w;
    const float4* p = (const float4*)(x + (size_t)row * D) + lane * 2;
    float4 v0 = p[0], v1 = p[1];
    float s = v0.x * v0.x + v0.y * v0.y + v0.z * v0.z + v0.w * v0.w
            + v1.x * v1.x + v1.y * v1.y + v1.z * v1.z + v1.w * v1.w;
    int w0 = __builtin_amdgcn_cvt_pk_fp8_f32(v0.x, v0.y, 0, false);
    w0     = __builtin_amdgcn_cvt_pk_fp8_f32(v0.z, v0.w, w0, true);
    int w1 = __builtin_amdgcn_cvt_pk_fp8_f32(v1.x, v1.y, 0, false);
    w1     = __builtin_amdgcn_cvt_pk_fp8_f32(v1.z, v1.w, w1, true);
    ((int2*)(x8 + (size_t)row * D))[lane] = make_int2(w0, w1);
    #pragma unroll
    for (int o = 32; o > 0; o >>= 1) s += __shfl_xor(s, o);
    if (lane == 0) {
        sq[row] = s;
        apU[row] = 0u;                 // max-d^2 accumulator (d^2 clamped >= 0)
        anU[row] = 0x7f800000u;        // min-d^2 accumulator (+inf)
    }
}

// 128x128 brick, MX-fp8 (K=128) MFMA, scales = 1.0 (0x7F E8M0) -> HW identity.
// 4 waves: wave (wm,wn) owns the 64x64 sub-tile; acc[4][4] = 64 AGPRs/lane.
//
// K-loop: double-buffered tiles, ONE raw s_barrier per iter, every waitcnt on
// stale ops. Pipeline: prologue stages tiles 0,1. Iter kk: vmcnt (tile kk's
// own loads landed; >=1 iter old except iter 0) -> s_barrier (all waves: tile
// kk complete AND tile kk-1's reads finished) -> stage tile kk+1 into tile
// kk-1's buffer (safe by the barrier; it's the OTHER buffer from tile kk) ->
// frag ds_reads -> MFMAs (compiler inserts the lgkm waits). No fresh lgkm
// drain, no second barrier, no setprio (lockstep GEMM: m190 null/negative).
// Gram-matrix property: A and B fragments use the SAME loader, so any
// consistent K-permutation cancels. Diagonal bricks (rowBase==colBase) stage
// B redundantly -- correct, and only 64/2080 bricks.
__device__ __forceinline__ void brick_body(
    int rowBase, int colBase,
    const unsigned char* __restrict__ xb, const float* __restrict__ sq,
    const int* __restrict__ tgt,
    unsigned int* __restrict__ apU, unsigned int* __restrict__ anU,
    char* smem_raw, float* sqI, float* sqJ, int* tI, int* tJ) {
    unsigned char* A0 = (unsigned char*)smem_raw;           // [0K,16K)
    unsigned char* B0 = A0 + 16384;                         // [16K,32K)
    unsigned char* A1 = A0 + 32768;                         // [32K,48K)
    unsigned char* B1 = A0 + 49152;                         // [48K,64K)
    float* redAp = (float*)smem_raw;                        // [128][34] (post-loop)
    float* redAn = redAp + 128 * 34;
    float* colAp = (float*)smem_raw;                        // [128][10] (phase 2)
    float* colAn = colAp + 128 * 10;

    const int tid = threadIdx.x;
    const int w = tid >> 6, lane = tid & 63, q = lane >> 4, c = lane & 15;
    const int wm = w & 1, wn = w >> 1;                      // 64x64 sub-tile per wave

    if (tid < 128) {
        sqI[tid] = sq[rowBase + tid]; tI[tid] = tgt[rowBase + tid];
        sqJ[tid] = sq[colBase + tid]; tJ[tid] = tgt[colBase + tid];
    }

    const unsigned char* Ag = xb + (size_t)rowBase * D;
    const unsigned char* Bg = xb + (size_t)colBase * D;

    f32x4 acc[4][4] = {};

    stage_tile(Ag, A0, Bg, B0, tid, 0);                     // tile 0
    stage_tile(Ag, A1, Bg, B1, tid, 128);                   // tile 1

    #pragma unroll
    for (int kk = 0; kk < 4; kk++) {                        // 4 K-iterations
        unsigned char* Asm = (kk & 1) ? A1 : A0;
        unsigned char* Bsm = (kk & 1) ? B1 : B0;
        // Own tile-kk loads landed. FIFO: iter 0 has 16 outstanding (tiles
        // 0,1) -> vmcnt(8); afterwards the only outstanding tile is >=1 full
        // iteration old -> vmcnt(0) is (nearly) free.
        if (kk == 0) asm volatile("s_waitcnt vmcnt(8)" ::: "memory");
        else         asm volatile("s_waitcnt vmcnt(0)" ::: "memory");
        asm volatile("s_barrier" ::: "memory");             // no implicit drains
        __builtin_amdgcn_sched_barrier(0);                  // pin: nothing crosses up

        if (kk == 1) stage_tile(Ag, A0, Bg, B0, tid, 256);  // tile 2 -> buf0
        if (kk == 2) stage_tile(Ag, A1, Bg, B1, tid, 384);  // tile 3 -> buf1

        int8v af[4], bf[4];
        #pragma unroll
        for (int t = 0; t < 4; t++)
            af[t] = load_frag8(Asm, wm * 64 + t * 16 + c, q);
        #pragma unroll
        for (int t = 0; t < 4; t++)
            bf[t] = load_frag8(Bsm, wn * 64 + t * 16 + c, q);

        #pragma unroll
        for (int tm = 0; tm < 4; tm++)
            #pragma unroll
            for (int t = 0; t < 4; t++)
                acc[tm][t] = __builtin_amdgcn_mfma_scale_f32_16x16x128_f8f6f4(
                    af[tm], bf[t], acc[tm][t],
                    0, 0,                                    // FMT A,B = fp8 e4m3
                    0, 0x7F7F7F7Fu, 0, 0x7F7F7F7Fu);         // scales = 1.0
    }
    __syncthreads();    // all waves' K-loop done -> tiles dead, scratch aliases

    // Epilogue. C/D layout is shape-determined: col=lane&15, row=q*4+reg.
    // d^2-space selection keys; both row-side and col-side (symmetry).
    float sjc[4]; int tjx[4];
    #pragma unroll
    for (int tn = 0; tn < 4; tn++) {
        int col_l = wn * 64 + tn * 16 + c;
        sjc[tn] = sqJ[col_l]; tjx[tn] = tJ[col_l];
    }
    float apc[4], anc[4];
    #pragma unroll
    for (int tn = 0; tn < 4; tn++) { apc[tn] = -1e30f; anc[tn] = 1e30f; }
    #pragma unroll
    for (int tm = 0; tm < 4; tm++) {
        #pragma unroll
        for (int r = 0; r < 4; r++) {
            int row_l = wm * 64 + tm * 16 + q * 4 + r;
            float si = sqI[row_l]; int ti = tI[row_l];
            float rp = -1e30f, rn = 1e30f;
            #pragma unroll
            for (int tn = 0; tn < 4; tn++) {
                float p = acc[tm][tn][r];
                bool same = (ti == tjx[tn]);
                float rk = fmaf(-2.0f, p, sjc[tn]);         // row-side key
                float ck = fmaf(-2.0f, p, si);              // col-side key
                rp = fmaxf(rp, same ? rk : -1e30f);
                rn = fminf(rn, same ? 1e30f : rk);
                apc[tn] = fmaxf(apc[tn], same ? ck : -1e30f);
                anc[tn] = fminf(anc[tn], same ? 1e30f : ck);
            }
            redAp[row_l * 34 + wn * 16 + c] = rp;
            redAn[row_l * 34 + wn * 16 + c] = rn;
        }
    }
    __syncthreads();
    if (tid < 128) {                                        // row finalize
        float ap = -1e30f, an = 1e30f;
        #pragma unroll 8
        for (int u = 0; u < 32; u++) {
            ap = fmaxf(ap, redAp[tid * 34 + u]);
            an = fminf(an, redAn[tid * 34 + u]);
        }
        // restore true d^2, clamp >=0 so uint-bit compare == float compare
        float apd = fmaxf(sqI[tid] + ap, 0.0f);
        float and_ = fmaxf(sqI[tid] + an, 0.0f);
        atomicMax(&apU[rowBase + tid], __float_as_uint(apd));
        atomicMin(&anU[rowBase + tid], __float_as_uint(and_));
    }
    __syncthreads();                                        // row phase done
    #pragma unroll
    for (int tn = 0; tn < 4; tn++) {
        int col_l = wn * 64 + tn * 16 + c;
        colAp[col_l * 10 + wm * 4 + q] = apc[tn];
        colAn[col_l * 10 + wm * 4 + q] = anc[tn];
    }
    __syncthreads();
    if (tid < 128) {                                        // col finalize
        float ap = -1e30f, an = 1e30f;
        #pragma unroll
        for (int u = 0; u < 8; u++) {
            ap = fmaxf(ap, colAp[tid * 10 + u]);
            an = fminf(an, colAn[tid * 10 + u]);
        }
        float apd = fmaxf(sqJ[tid] + ap, 0.0f);
        float and_ = fmaxf(sqJ[tid] + an, 0.0f);
        atomicMax(&apU[colBase + tid], __float_as_uint(apd));  // fire-and-forget
        atomicMin(&anU[colBase + tid], __float_as_uint(and_));
    }
}

// Kernel 2: blocks 0..2015 = off-diagonal 128x128 bricks (ri < cj, triangular
// index); blocks 2016..2079 = diagonal bricks, dispatched LAST.
// 256 threads, ~68 KB LDS, ~180 regs/lane -> 2 blocks/CU (8 waves/CU), two
// INDEPENDENT blocks per CU hide each other's residual stalls (m114).
__global__ __launch_bounds__(256, 2)
void gemm_kernel(const unsigned char* __restrict__ xb,
                 const float* __restrict__ sq,
                 const int* __restrict__ tgt,
                 unsigned int* __restrict__ apU,
                 unsigned int* __restrict__ anU) {
    __shared__ __align__(16) char smem_raw[65536];          // 2 x (A 16K + B 16K)
    __shared__ float sqI[128], sqJ[128];
    __shared__ int tI[128], tJ[128];

    const int id = blockIdx.x;
    int ri, cj;
    if (id < NFULLP) {
        cj = (int)((1.0f + sqrtf(1.0f + 8.0f * (float)id)) * 0.5f);
        while (cj * (cj - 1) / 2 > id) cj--;
        while ((cj + 1) * cj / 2 <= id) cj++;
        ri = id - cj * (cj - 1) / 2;                        // 0..cj-1
    } else {
        ri = cj = id - NFULLP;                              // diagonal
    }
    brick_body(ri * 128, cj * 128, xb, sq, tgt, apU, anU,
               smem_raw, sqI, sqJ, tI, tJ);
}

// Kernel 3: per-row ap/an final in apU/anU -> sqrt + relu + mean; last block
// (atomic counter) folds the 32 block sums into out[0].
__global__ void reduce_kernel(const unsigned int* __restrict__ apU,
                              const unsigned int* __restrict__ anU,
                              float* __restrict__ bsum, int* __restrict__ cnt,
                              float* __restrict__ out) {
    int tid = threadIdx.x;
    int row = blockIdx.x * 256 + tid;
    float ap = __uint_as_float(apU[row]);
    float an = __uint_as_float(anU[row]);
    float dap = sqrtf(fmaxf(ap, 1e-12f));
    float dan = sqrtf(fmaxf(an, 1e-12f));
    float v = fmaxf(dap - dan + MARGIN, 0.0f);
    #pragma unroll
    for (int o = 32; o > 0; o >>= 1) v += __shfl_xor(v, o);
    __shared__ float ss[4];
    __shared__ int amLast;
    if ((tid & 63) == 0) ss[tid >> 6] = v;
    __syncthreads();
    if (tid == 0) {
        bsum[blockIdx.x] = ss[0] + ss[1] + ss[2] + ss[3];
        __threadfence();
        amLast = (atomicAdd(cnt, 1) == N / 256 - 1);
    }
    __syncthreads();
    if (amLast && tid < 64) {
        __threadfence();
        float t = (tid < N / 256) ? bsum[tid] : 0.0f;
        #pragma unroll
        for (int o = 32; o > 0; o >>= 1) t += __shfl_xor(t, o);
        if (tid == 0) out[0] = t * (1.0f / (float)N);
    }
}

extern "C" void kernel_launch(void* const* d_in, const int* in_sizes, int n_in,
                              void* d_out, int out_size, void* d_ws, size_t ws_size,
                              hipStream_t stream) {
    const float* x  = (const float*)d_in[0];
    const int* tgt  = (const int*)d_in[1];
    float* out      = (float*)d_out;

    char* ws = (char*)d_ws;
    unsigned char* x8 = (unsigned char*)ws;                         // 4 MB fp8 X
    float* sq   = (float*)(ws + (size_t)N * D);                     // 32 KB
    unsigned int* apU = (unsigned int*)(sq + N);                    // 32 KB
    unsigned int* anU = apU + N;                                    // 32 KB
    float* bsum = (float*)(anU + N);                                // 128 B
    int* cnt = (int*)(bsum + 32);

    prep_kernel<<<N / 4, 256, 0, stream>>>(x, x8, sq, apU, anU, cnt);
    gemm_kernel<<<NBRICKS, 256, 0, stream>>>(x8, sq, tgt, apU, anU);
    reduce_kernel<<<N / 256, 256, 0, stream>>>(apU, anU, bsum, cnt, out);
}